// Round 4
// baseline (346.162 us; speedup 1.0000x reference)
//
#include <hip/hip_runtime.h>

// Problem: frames [4][B=8][C=64][H=160][W=160] fp32.
// Per pixel: p_ij[c] = x_i[c]*x_j[c] (symmetric), softmax over (j,c) per i,
// out_i[c] = sum_j softmax_i[j,c] * x_j[c]. Output [B][4C][H][W].
//
// Memory-bound (~420 MB mandatory traffic; mixed-stream floor ~72 us).
// This version targets HBM read-stream continuity + occupancy:
//  - single-buffer continuous pipeline: inside the fused drain loop, right
//    after pf[it] is ds_written to LDS, pf[it] is RE-ISSUED with tile k+2.
//    ds_write consumes the register at issue (in-order), so one register set
//    keeps reads in flight across drain -> barrier -> compute -> barrier.
//    Previous version had zero reads in flight during every drain phase.
//  - 512-thread blocks: wave occupancy 16 -> 24 waves/CU (3 blocks x 8 waves,
//    launch_bounds(512,6) caps VGPR at ~80, comfortably above est. usage).
//    Staging map is identical as a function of q -> bank-conflict geometry
//    (2-way max = free) unchanged.
//  - non-temporal loads/stores retained (touch-once streams).

#define HW 25600          // 160*160
#define NP 32             // pixels per tile
#define ROW 257           // 256 channels + 1 pad (2-way max conflicts, free)
#define TPB 4             // tiles per block
#define BLOCKS_PER_B 200  // (HW/NP)/TPB
#define NTH 512           // threads per block
#define SIT 4             // staging float4 per thread = NP*256/(4*NTH)

typedef float f32x4 __attribute__((ext_vector_type(4)));

__device__ __forceinline__ float wave_allsum(float x) {
  // Full wave64 add-reduction, result broadcast to all lanes.
  int v;
  v = __builtin_amdgcn_update_dpp(0, __float_as_int(x), 0xB1, 0xf, 0xf, true);  // quad_perm [1,0,3,2]
  x += __int_as_float(v);
  v = __builtin_amdgcn_update_dpp(0, __float_as_int(x), 0x4E, 0xf, 0xf, true);  // quad_perm [2,3,0,1]
  x += __int_as_float(v);
  v = __builtin_amdgcn_update_dpp(0, __float_as_int(x), 0x141, 0xf, 0xf, true); // row_half_mirror
  x += __int_as_float(v);
  v = __builtin_amdgcn_update_dpp(0, __float_as_int(x), 0x140, 0xf, 0xf, true); // row_mirror
  x += __int_as_float(v);
  v = __builtin_amdgcn_update_dpp(0, __float_as_int(x), 0x142, 0xa, 0xf, false); // row_bcast15
  x += __int_as_float(v);
  v = __builtin_amdgcn_update_dpp(0, __float_as_int(x), 0x143, 0xc, 0xf, false); // row_bcast31
  x += __int_as_float(v);
  return __int_as_float(__builtin_amdgcn_readlane(__float_as_int(x), 63));
}

__global__ __launch_bounds__(NTH, 6) void fused_frame_softmax(
    const float* __restrict__ in, float* __restrict__ out) {
  __shared__ float Xs[NP * ROW];

  const int b     = blockIdx.x / BLOCKS_PER_B;
  const int pbase = (blockIdx.x % BLOCKS_PER_B) * (TPB * NP);
  const int t     = threadIdx.x;

  // Staging geometry (it = 0..SIT-1): q = it*NTH + t
  //   ch = q>>3 (= j*64+c), pq = (q&7)*4 (4 consecutive pixels)
  // input  element offset: ((ch>>6)*512 + b*64 + (ch&63))*HW + px
  // output element offset: (b*256 + ch)*HW + px

  f32x4 pf[SIT];

  // ---- tile 0: load -> registers -> scatter-transpose into LDS ----
  #pragma unroll
  for (int it = 0; it < SIT; ++it) {
    const int q  = it * NTH + t;
    const int ch = q >> 3;
    const int pq = (q & 7) << 2;
    const int off = ((ch >> 6) * 512 + b * 64 + (ch & 63)) * HW + pbase + pq;
    pf[it] = __builtin_nontemporal_load(reinterpret_cast<const f32x4*>(in + off));
  }
  #pragma unroll
  for (int it = 0; it < SIT; ++it) {
    const int q  = it * NTH + t;
    const int ch = q >> 3;
    const int pq = (q & 7) << 2;
    Xs[(pq + 0) * ROW + ch] = pf[it].x;
    Xs[(pq + 1) * ROW + ch] = pf[it].y;
    Xs[(pq + 2) * ROW + ch] = pf[it].z;
    Xs[(pq + 3) * ROW + ch] = pf[it].w;
  }
  __syncthreads();

  // ---- issue tile 1 loads; they fly under compute(0) ----
  #pragma unroll
  for (int it = 0; it < SIT; ++it) {
    const int q  = it * NTH + t;
    const int ch = q >> 3;
    const int pq = (q & 7) << 2;
    const int off = ((ch >> 6) * 512 + b * 64 + (ch & 63)) * HW + pbase + NP + pq;
    pf[it] = __builtin_nontemporal_load(reinterpret_cast<const f32x4*>(in + off));
  }

  const int lane  = t & 63;
  const int wbase = (t >> 6) * 4;  // 8 waves x 4 pixels each

  #pragma unroll
  for (int k = 0; k < TPB; ++k) {
    // ---- compute: one wave per pixel, lane = channel, in-place in LDS ----
    #pragma unroll 2
    for (int pp = 0; pp < 4; ++pp) {
      float* row = Xs + (wbase + pp) * ROW;
      const float x0 = row[lane];
      const float x1 = row[lane + 64];
      const float x2 = row[lane + 128];
      const float x3 = row[lane + 192];

      // 10 unique exp(p_ij); shift-free (softmax shift-invariance; N(0,1)
      // inputs keep |p| well inside fp32 exp range).
      const float E00 = __expf(x0 * x0);
      const float E01 = __expf(x0 * x1);
      const float E02 = __expf(x0 * x2);
      const float E03 = __expf(x0 * x3);
      const float E11 = __expf(x1 * x1);
      const float E12 = __expf(x1 * x2);
      const float E13 = __expf(x1 * x3);
      const float E22 = __expf(x2 * x2);
      const float E23 = __expf(x2 * x3);
      const float E33 = __expf(x3 * x3);

      const float z0 = wave_allsum(E00 + E01 + E02 + E03);
      const float z1 = wave_allsum(E01 + E11 + E12 + E13);
      const float z2 = wave_allsum(E02 + E12 + E22 + E23);
      const float z3 = wave_allsum(E03 + E13 + E23 + E33);

      const float r0 = __builtin_amdgcn_rcpf(z0);
      const float r1 = __builtin_amdgcn_rcpf(z1);
      const float r2 = __builtin_amdgcn_rcpf(z2);
      const float r3 = __builtin_amdgcn_rcpf(z3);

      row[lane]       = (E00 * x0 + E01 * x1 + E02 * x2 + E03 * x3) * r0;
      row[lane + 64]  = (E01 * x0 + E11 * x1 + E12 * x2 + E13 * x3) * r1;
      row[lane + 128] = (E02 * x0 + E12 * x1 + E22 * x2 + E23 * x3) * r2;
      row[lane + 192] = (E03 * x0 + E13 * x1 + E23 * x2 + E33 * x3) * r3;
    }
    __syncthreads();

    // ---- fused drain(k) + fill(k+1) + RE-ISSUE load(k+2) ----
    // Per-thread LDS addresses form a bijection with (px,ch), so the
    // read-then-overwrite needs no extra barrier. pf[it] is consumed by the
    // ds_write (register read at issue, in-order), so the immediately
    // following global_load may safely retarget it: tile k+2's reads stay
    // in flight through the barrier and all of compute(k+1).
    #pragma unroll
    for (int it = 0; it < SIT; ++it) {
      const int q  = it * NTH + t;
      const int ch = q >> 3;
      const int pq = (q & 7) << 2;
      f32x4 v;
      v.x = Xs[(pq + 0) * ROW + ch];
      v.y = Xs[(pq + 1) * ROW + ch];
      v.z = Xs[(pq + 2) * ROW + ch];
      v.w = Xs[(pq + 3) * ROW + ch];
      if (k + 1 < TPB) {
        Xs[(pq + 0) * ROW + ch] = pf[it].x;
        Xs[(pq + 1) * ROW + ch] = pf[it].y;
        Xs[(pq + 2) * ROW + ch] = pf[it].z;
        Xs[(pq + 3) * ROW + ch] = pf[it].w;
      }
      if (k + 2 < TPB) {
        const int off =
            ((ch >> 6) * 512 + b * 64 + (ch & 63)) * HW + pbase + (k + 2) * NP + pq;
        pf[it] = __builtin_nontemporal_load(
            reinterpret_cast<const f32x4*>(in + off));
      }
      const int ooff = (b * 256 + ch) * HW + pbase + k * NP + pq;
      __builtin_nontemporal_store(v, reinterpret_cast<f32x4*>(out + ooff));
    }
    __syncthreads();
  }
}

extern "C" void kernel_launch(void* const* d_in, const int* in_sizes, int n_in,
                              void* d_out, int out_size, void* d_ws, size_t ws_size,
                              hipStream_t stream) {
  const float* in = (const float*)d_in[0];
  float* out      = (float*)d_out;
  // 8 batches * 200 blocks * 4 tiles of 32 pixels; 512 threads/block
  fused_frame_softmax<<<dim3(8 * BLOCKS_PER_B), dim3(NTH), 0, stream>>>(in, out);
}